// Round 1
// baseline (488.107 us; speedup 1.0000x reference)
//
#include <hip/hip_runtime.h>

// DIN attention unit, MI355X.
// B=512, T=2048, D=20. Tower 80->32->16->1 with Dice (batch-norm stats over
// all B*T positions per channel). mask input is UNUSED (reference reproduces
// the original bug: unmasked scores are used for the final matmul).
//
// 3 sweeps over keys (recompute h0/h1 instead of storing 134/67 MB):
//   pass1: h0_pre -> per-channel sum/sumsq (32 ch)
//   fin0 : mean/var -> scale/shift
//   pass2: h0_pre -> dice0 -> h1_pre -> sum/sumsq (16 ch)
//   fin1 : mean/var -> scale/shift
//   pass3: full tower -> score -> out[b,d] = sum_t score*keys
//
// Layer weights are per-lane REGISTERS (channel-per-lane): layer1 lane=j(32),
// layer2 lane=jj(16); activations flow through LDS tiles of 16 positions.

#define BB 512
#define TT 2048
#define DD 20
#define C0 32
#define C1 16
#define BPB 4              // blocks per batch
#define TCHUNK (TT / BPB)  // 512 positions per block
#define NTHREADS 256

// ws float offsets
#define WS_SUM0 0
#define WS_SQ0 32
#define WS_SUM1 64
#define WS_SQ1 80
#define WS_SCALE0 96
#define WS_SHIFT0 128
#define WS_SCALE1 160
#define WS_SHIFT1 176

__device__ __forceinline__ float fast_sigmoid(float x) {
    return __builtin_amdgcn_rcpf(1.0f + __expf(-x));
}

// Compute per-lane layer-1 weights: wM[d] and cj for channel j of batch b.
__device__ __forceinline__ void layer1_weights(const float* __restrict__ W0,
                                               const float* __restrict__ b0,
                                               const float* qs, int j,
                                               float* wM, float& cj) {
    cj = b0[j];
#pragma unroll
    for (int d = 0; d < DD; ++d) {
        float w_q = W0[d * C0 + j];
        float w_k = W0[(DD + d) * C0 + j];
        float w_d = W0[(2 * DD + d) * C0 + j];
        float w_p = W0[(3 * DD + d) * C0 + j];
        float qd = qs[d];
        wM[d] = w_k - w_d + qd * w_p;
        cj = fmaf(qd, w_q + w_d, cj);
    }
}

__device__ __forceinline__ void load_krow(const float* __restrict__ kb, int p,
                                          float* kk) {
    const float4* kr = (const float4*)(kb + (size_t)p * DD);
    float4 k0 = kr[0], k1 = kr[1], k2 = kr[2], k3 = kr[3], k4 = kr[4];
    kk[0] = k0.x; kk[1] = k0.y; kk[2] = k0.z; kk[3] = k0.w;
    kk[4] = k1.x; kk[5] = k1.y; kk[6] = k1.z; kk[7] = k1.w;
    kk[8] = k2.x; kk[9] = k2.y; kk[10] = k2.z; kk[11] = k2.w;
    kk[12] = k3.x; kk[13] = k3.y; kk[14] = k3.z; kk[15] = k3.w;
    kk[16] = k4.x; kk[17] = k4.y; kk[18] = k4.z; kk[19] = k4.w;
}

// ---------------- pass 1: layer1 pre-activation stats ----------------
__global__ __launch_bounds__(NTHREADS) void pass1_kernel(
    const float* __restrict__ keys, const float* __restrict__ query,
    const float* __restrict__ W0, const float* __restrict__ b0,
    float* __restrict__ ws) {
    const int b = blockIdx.y, chunk = blockIdx.x, tid = threadIdx.x;
    const int j = tid & 31, grp = tid >> 5;  // channel, position-slot (0..7)

    __shared__ float qs[DD];
    __shared__ float red[4][64];
    if (tid < DD) qs[tid] = query[b * DD + tid];
    __syncthreads();

    float wM[DD], cj;
    layer1_weights(W0, b0, qs, j, wM, cj);

    const float* kb = keys + ((size_t)b * TT + chunk * TCHUNK) * DD;
    float s = 0.f, q2 = 0.f;
    for (int it = 0; it < TCHUNK / 8; ++it) {
        float kk[DD];
        load_krow(kb, it * 8 + grp, kk);
        float h = cj;
#pragma unroll
        for (int d = 0; d < DD; ++d) h = fmaf(kk[d], wM[d], h);
        s += h;
        q2 = fmaf(h, h, q2);
    }
    // combine grp pairs within wave, then across 4 waves via LDS
    s += __shfl_xor(s, 32);
    q2 += __shfl_xor(q2, 32);
    const int wave = tid >> 6, lane = tid & 63;
    if (lane < 32) {
        red[wave][j] = s;
        red[wave][32 + j] = q2;
    }
    __syncthreads();
    if (tid < 64) {
        float v = red[0][tid] + red[1][tid] + red[2][tid] + red[3][tid];
        atomicAdd(&ws[WS_SUM0 + tid], v);  // [0..31]=sum, [32..63]=sumsq
    }
}

// ---------------- finalize: mean/var -> scale/shift ----------------
__global__ void finalize_kernel(float* __restrict__ ws, int nch, int sumOff,
                                int sqOff, int scOff, int shOff) {
    int j = threadIdx.x;
    if (j < nch) {
        const float invN = 1.0f / (float)(BB * TT);
        float mean = ws[sumOff + j] * invN;
        float ex2 = ws[sqOff + j] * invN;
        float var = ex2 - mean * mean;
        float sc = rsqrtf(var + 1e-9f);
        ws[scOff + j] = sc;
        ws[shOff + j] = -mean * sc;
    }
}

// ---------------- pass 2: layer2 pre-activation stats ----------------
__global__ __launch_bounds__(NTHREADS) void pass2_kernel(
    const float* __restrict__ keys, const float* __restrict__ query,
    const float* __restrict__ W0, const float* __restrict__ b0,
    const float* __restrict__ a0, const float* __restrict__ W1,
    const float* __restrict__ b1, float* __restrict__ ws) {
    const int b = blockIdx.y, chunk = blockIdx.x, tid = threadIdx.x;
    const int j = tid & 31, grp = tid >> 5;   // layer1 role
    const int jj = tid & 15, pg2 = tid >> 4;  // layer2 role (16 positions)

    __shared__ float qs[DD];
    __shared__ float h0buf[16][33];  // +1 pad: layer2 reads conflict-free
    __shared__ float red2[4][32];
    if (tid < DD) qs[tid] = query[b * DD + tid];
    __syncthreads();

    float wM[DD], cj;
    layer1_weights(W0, b0, qs, j, wM, cj);
    const float sc0 = ws[WS_SCALE0 + j], sh0 = ws[WS_SHIFT0 + j];
    const float al0 = a0[j];

    float w1c[C0];
#pragma unroll
    for (int l = 0; l < C0; ++l) w1c[l] = W1[l * C1 + jj];
    const float b1j = b1[jj];

    const float* kb = keys + ((size_t)b * TT + chunk * TCHUNK) * DD;
    float s1 = 0.f, q12 = 0.f;

    for (int tile = 0; tile < TCHUNK / 16; ++tile) {
#pragma unroll
        for (int sub = 0; sub < 2; ++sub) {
            int row = sub * 8 + grp;
            float kk[DD];
            load_krow(kb, tile * 16 + row, kk);
            float h = cj;
#pragma unroll
            for (int d = 0; d < DD; ++d) h = fmaf(kk[d], wM[d], h);
            float p = fast_sigmoid(fmaf(h, sc0, sh0));
            h0buf[row][j] = h * (al0 + p * (1.0f - al0));
        }
        __syncthreads();
        float h1 = b1j;
#pragma unroll
        for (int l = 0; l < C0; ++l) h1 = fmaf(h0buf[pg2][l], w1c[l], h1);
        s1 += h1;
        q12 = fmaf(h1, h1, q12);
        __syncthreads();
    }
    s1 += __shfl_xor(s1, 16);
    s1 += __shfl_xor(s1, 32);
    q12 += __shfl_xor(q12, 16);
    q12 += __shfl_xor(q12, 32);
    const int wave = tid >> 6, lane = tid & 63;
    if (lane < 16) {
        red2[wave][jj] = s1;
        red2[wave][16 + jj] = q12;
    }
    __syncthreads();
    if (tid < 32) {
        float v = red2[0][tid] + red2[1][tid] + red2[2][tid] + red2[3][tid];
        atomicAdd(&ws[WS_SUM1 + tid], v);  // [64..79]=sum1, [80..95]=sq1
    }
}

// ---------------- pass 3: full tower + weighted key-sum ----------------
__global__ __launch_bounds__(NTHREADS) void pass3_kernel(
    const float* __restrict__ keys, const float* __restrict__ query,
    const float* __restrict__ W0, const float* __restrict__ b0,
    const float* __restrict__ a0, const float* __restrict__ W1,
    const float* __restrict__ b1, const float* __restrict__ a1,
    const float* __restrict__ wk, const float* __restrict__ bk,
    const float* __restrict__ ws, float* __restrict__ out) {
    const int b = blockIdx.y, chunk = blockIdx.x, tid = threadIdx.x;
    const int j = tid & 31, grp = tid >> 5;
    const int jj = tid & 15, pg2 = tid >> 4;
    const int dlane = tid & 31, pg = tid >> 5;  // output role

    __shared__ float qs[DD];
    __shared__ float h0buf[16][33];
    __shared__ float sbuf[16];
    __shared__ float outred[8][DD];
    if (tid < DD) qs[tid] = query[b * DD + tid];
    __syncthreads();

    float wM[DD], cj;
    layer1_weights(W0, b0, qs, j, wM, cj);
    const float sc0 = ws[WS_SCALE0 + j], sh0 = ws[WS_SHIFT0 + j];
    const float al0 = a0[j];

    float w1c[C0];
#pragma unroll
    for (int l = 0; l < C0; ++l) w1c[l] = W1[l * C1 + jj];
    const float b1j = b1[jj];
    const float sc1 = ws[WS_SCALE1 + jj], sh1 = ws[WS_SHIFT1 + jj];
    const float al1 = a1[jj];
    const float wkj = wk[jj];
    const float bkv = bk[0];

    const float* kb = keys + ((size_t)b * TT + chunk * TCHUNK) * DD;
    float accD = 0.f;

    for (int tile = 0; tile < TCHUNK / 16; ++tile) {
#pragma unroll
        for (int sub = 0; sub < 2; ++sub) {
            int row = sub * 8 + grp;
            float kk[DD];
            load_krow(kb, tile * 16 + row, kk);
            float h = cj;
#pragma unroll
            for (int d = 0; d < DD; ++d) h = fmaf(kk[d], wM[d], h);
            float p = fast_sigmoid(fmaf(h, sc0, sh0));
            h0buf[row][j] = h * (al0 + p * (1.0f - al0));
        }
        __syncthreads();
        {
            float h1 = b1j;
#pragma unroll
            for (int l = 0; l < C0; ++l) h1 = fmaf(h0buf[pg2][l], w1c[l], h1);
            float p1 = fast_sigmoid(fmaf(h1, sc1, sh1));
            float h1d = h1 * (al1 + p1 * (1.0f - al1));
            float sc = h1d * wkj;
            sc += __shfl_xor(sc, 1);
            sc += __shfl_xor(sc, 2);
            sc += __shfl_xor(sc, 4);
            sc += __shfl_xor(sc, 8);
            if (jj == 0) sbuf[pg2] = sc + bkv;
        }
        __syncthreads();
        if (dlane < DD) {
            int p0 = tile * 16 + pg;
            accD = fmaf(sbuf[pg], kb[(size_t)p0 * DD + dlane], accD);
            accD = fmaf(sbuf[pg + 8], kb[(size_t)(p0 + 8) * DD + dlane], accD);
        }
        // no sync needed here: next-tile h0buf writes don't touch sbuf, and
        // next-tile sbuf writes are behind the next __syncthreads() pair.
    }
    if (dlane < DD) outred[pg][dlane] = accD;
    __syncthreads();
    if (tid < DD) {
        float v = 0.f;
#pragma unroll
        for (int g = 0; g < 8; ++g) v += outred[g][tid];
        atomicAdd(&out[b * DD + tid], v);
    }
}

extern "C" void kernel_launch(void* const* d_in, const int* in_sizes, int n_in,
                              void* d_out, int out_size, void* d_ws,
                              size_t ws_size, hipStream_t stream) {
    const float* keys = (const float*)d_in[0];
    const float* query = (const float*)d_in[1];
    // d_in[2] = mask: intentionally unused (reference uses unmasked scores)
    const float* W0 = (const float*)d_in[3];
    const float* b0 = (const float*)d_in[4];
    const float* a0 = (const float*)d_in[5];
    const float* W1 = (const float*)d_in[6];
    const float* b1 = (const float*)d_in[7];
    const float* a1 = (const float*)d_in[8];
    const float* wk = (const float*)d_in[9];
    const float* bk = (const float*)d_in[10];
    float* out = (float*)d_out;
    float* ws = (float*)d_ws;

    // ws/out are poisoned 0xAA before every launch -> zero what we accumulate
    hipMemsetAsync(ws, 0, 96 * sizeof(float), stream);
    hipMemsetAsync(out, 0, (size_t)out_size * sizeof(float), stream);

    dim3 grid(BPB, BB), blk(NTHREADS);
    pass1_kernel<<<grid, blk, 0, stream>>>(keys, query, W0, b0, ws);
    finalize_kernel<<<1, 32, 0, stream>>>(ws, 32, WS_SUM0, WS_SQ0, WS_SCALE0,
                                          WS_SHIFT0);
    pass2_kernel<<<grid, blk, 0, stream>>>(keys, query, W0, b0, a0, W1, b1, ws);
    finalize_kernel<<<1, 16, 0, stream>>>(ws, 16, WS_SUM1, WS_SQ1, WS_SCALE1,
                                          WS_SHIFT1);
    pass3_kernel<<<grid, blk, 0, stream>>>(keys, query, W0, b0, a0, W1, b1, a1,
                                           wk, bk, ws, out);
}